// Round 11
// baseline (837.680 us; speedup 1.0000x reference)
//
#include <hip/hip_runtime.h>

#define B_ 2
#define N_ 2048
#define M_ 2048
#define D_ 256
#define H_ 8
#define DH_ 32
#define SPLITS 2
#define NBLK 1024
// 1/sqrt(32) * log2(e): fold into q projection; attention works in exp2 domain
#define QSCALE (0.17677669529663689f * 1.4426950408889634f)

typedef __attribute__((ext_vector_type(8))) short short8;
typedef __attribute__((ext_vector_type(4))) float f32x4;
typedef unsigned short u16;
typedef unsigned int u32;

#if __has_builtin(__builtin_amdgcn_exp2f)
#define EXP2 __builtin_amdgcn_exp2f
#else
#define EXP2 exp2f
#endif

__device__ __forceinline__ u16 f2bf(float f) {
  u32 u = __float_as_uint(f);
  return (u16)((u + 0x7fffu + ((u >> 16) & 1u)) >> 16);  // RNE
}
__device__ __forceinline__ u32 cvtpk_bf16(float lo, float hi) {
  u32 r;
  asm("v_cvt_pk_bf16_f32 %0, %1, %2" : "=v"(r) : "v"(lo), "v"(hi));
  return r;
}
__device__ __forceinline__ void gload_lds16(const u16* g, u16* l) {
  __builtin_amdgcn_global_load_lds((const __attribute__((address_space(1))) void*)g,
                                   (__attribute__((address_space(3))) void*)l, 16, 0, 0);
}
__device__ __forceinline__ void gload_lds16f(const float* g, float* l) {
  __builtin_amdgcn_global_load_lds((const __attribute__((address_space(1))) void*)g,
                                   (__attribute__((address_space(3))) void*)l, 16, 0, 0);
}

// Software grid barrier: all NBLK blocks co-resident (guaranteed by
// launch_bounds(256,4): VGPR<=128, LDS=32KB -> 4 blk/CU x 256 CU = 1024).
__device__ __forceinline__ void grid_sync(u32* cnt, u32 target) {
  __threadfence();  // release (agent-scope: L2 writeback)
  __syncthreads();
  if (threadIdx.x == 0) {
    atomicAdd(cnt, 1u);
    while (__hip_atomic_load(cnt, __ATOMIC_ACQUIRE, __HIP_MEMORY_SCOPE_AGENT) < target)
      __builtin_amdgcn_s_sleep(7);
  }
  __syncthreads();
  __threadfence();  // acquire (agent-scope: cache invalidate)
}

__global__ __launch_bounds__(256, 4) void fused_kernel(
    const float* __restrict__ Xq, const float* __restrict__ Xk, const float* __restrict__ Xv,
    const float* __restrict__ Wq, const float* __restrict__ Wk,
    const float* __restrict__ Wv, const float* __restrict__ Wo,
    const float* __restrict__ bq, const float* __restrict__ bk,
    const float* __restrict__ bv, const float* __restrict__ bo,
    const float* __restrict__ presence,
    u16* __restrict__ ximg, u16* __restrict__ wimg,
    u16* __restrict__ qb, u16* __restrict__ kb, u16* __restrict__ vtb,
    float* __restrict__ opart, float* __restrict__ lpart,
    float* __restrict__ out, u32* __restrict__ cnt) {
  __shared__ __align__(16) char smem[32768];
  const int t = threadIdx.x;
  const int g = blockIdx.x;
  const int wv = t >> 6, lane = t & 63, lr = lane & 15, lg = lane >> 4;

  // ================= Phase C: convert X and W to pre-swizzled bf16 images ====
  if (g < 768) {  // X: 12288 rows (3 inputs x 4096), 16 rows/block
    const int rl = t >> 4;
    const int gr = g * 16 + rl;
    const int gi = gr >> 12, rr = gr & 4095;
    const float* X = gi == 0 ? Xq : (gi == 1 ? Xk : Xv);
    const float* xp = X + (size_t)rr * D_ + (t & 15) * 16;
    u16* xo = ximg + ((size_t)gi * 4096 + rr) * D_;
    const int s0 = (t & 15) * 2;
    const f32x4 a0 = *(const f32x4*)(xp);
    const f32x4 a1 = *(const f32x4*)(xp + 4);
    const f32x4 a2 = *(const f32x4*)(xp + 8);
    const f32x4 a3 = *(const f32x4*)(xp + 12);
    uint4 v0, v1;
    v0.x = cvtpk_bf16(a0[0], a0[1]);
    v0.y = cvtpk_bf16(a0[2], a0[3]);
    v0.z = cvtpk_bf16(a1[0], a1[1]);
    v0.w = cvtpk_bf16(a1[2], a1[3]);
    v1.x = cvtpk_bf16(a2[0], a2[1]);
    v1.y = cvtpk_bf16(a2[2], a2[3]);
    v1.z = cvtpk_bf16(a3[0], a3[1]);
    v1.w = cvtpk_bf16(a3[2], a3[3]);
    *(uint4*)(xo + ((s0 ^ (rr & 7)) * 8)) = v0;
    *(uint4*)(xo + (((s0 + 1) ^ (rr & 7)) * 8)) = v1;
  } else if (g < 832) {  // W: r9-verified transpose-convert to swizzled image
    u16(*sh)[72] = (u16(*)[72])smem;
    const int blk = g - 768;
    const int mi = blk >> 4, tile = blk & 15;
    const float* Ws = mi == 0 ? Wq : mi == 1 ? Wk : mi == 2 ? Wv : Wo;
    u16* Wd = wimg + (size_t)mi * 65536;
    const int r0 = (tile >> 2) * 64, c0 = (tile & 3) * 64;
    const int r = t & 63, qt = t >> 6;
    const float* sp = Ws + (size_t)(r0 + r) * D_ + c0 + qt * 16;
    u32 w[8];
#pragma unroll
    for (int i = 0; i < 4; ++i) {
      f32x4 v = *(const f32x4*)(sp + i * 4);
      w[i * 2 + 0] = cvtpk_bf16(v[0], v[1]);
      w[i * 2 + 1] = cvtpk_bf16(v[2], v[3]);
    }
    *(uint4*)(&sh[r][qt * 16]) = *(uint4*)&w[0];
    *(uint4*)(&sh[r][qt * 16 + 8]) = *(uint4*)&w[4];
    __syncthreads();
    const int cc = t & 63;
    u32 t2[8];
#pragma unroll
    for (int i = 0; i < 8; ++i) {
      u32 lo = sh[qt * 16 + 2 * i][cc];
      u32 hi = sh[qt * 16 + 2 * i + 1][cc];
      t2[i] = lo | (hi << 16);
    }
    const int crow = c0 + cc;
    u16* rowb = Wd + (size_t)crow * D_;
    const int sl0 = (r0 + qt * 16) >> 3;  // even
    *(uint4*)(rowb + ((sl0 ^ (crow & 7)) * 8)) = *(uint4*)&t2[0];
    *(uint4*)(rowb + (((sl0 + 1) ^ (crow & 7)) * 8)) = *(uint4*)&t2[4];
  }
  grid_sync(cnt, NBLK);

  // ================= Phase P: q/k/v projections, 3072 DMA-staged 32x32 tasks ==
  {
    u16* ws = (u16*)smem;       // W^T slice: 32 rows x 512B
    u16* xsp = ws + 8192;       // X slice:   32 rows x 512B
    for (int tk = g; tk < 3072; tk += NBLK) {
      const int p = tk >> 10;
      const int rem = tk & 1023;
      const int nb = rem & 127, cb = rem >> 7;
      const int n0B = nb * 32, c0B = cb * 32;
      const u16* wsrc = wimg + (size_t)p * 65536 + (size_t)c0B * D_ + t * 8;
      const u16* xsrc = ximg + ((size_t)p * 4096 + n0B) * D_ + t * 8;
#pragma unroll
      for (int i = 0; i < 4; ++i) {
        gload_lds16(wsrc + i * 2048, ws + t * 8 + i * 2048);
        gload_lds16(xsrc + i * 2048, xsp + t * 8 + i * 2048);
      }
      __syncthreads();

      const f32x4 zz = {0.f, 0.f, 0.f, 0.f};
      f32x4 acc = zz;
      const int arow = (wv & 1) * 16 + lr;   // c within slice
      const int brow = (wv >> 1) * 16 + lr;  // n within slice
#pragma unroll
      for (int ks = 0; ks < 8; ++ks) {
        const short8 a = *(const short8*)(ws + arow * 256 + (((ks * 4 + lg) ^ (arow & 7)) * 8));
        const short8 b = *(const short8*)(xsp + brow * 256 + (((ks * 4 + lg) ^ (brow & 7)) * 8));
        acc = __builtin_amdgcn_mfma_f32_16x16x32_bf16(a, b, acc, 0, 0, 0);
      }
      // C: col(lr)=n, row(lg*4+j)=c
      const int cg4 = c0B + (wv & 1) * 16 + lg * 4;
      const int n = n0B + (wv >> 1) * 16 + lr;
      const int gb = n >> 11, nn = n & (N_ - 1);
      const float* bias = p == 0 ? bq : (p == 1 ? bk : bv);
      const f32x4 bias4 = *(const f32x4*)(bias + cg4);
      if (p < 2) {
        u16* obp = p == 0 ? qb : kb;
        const float sc = p == 0 ? QSCALE : 1.0f;
#pragma unroll
        for (int j = 0; j < 4; ++j) {
          const int c = cg4 + j;
          obp[((size_t)(gb * H_ + (c >> 5)) * N_ + nn) * DH_ + (c & 31)] =
              f2bf((acc[j] + bias4[j]) * sc);
        }
      } else {
#pragma unroll
        for (int j = 0; j < 4; ++j) {
          const int c = cg4 + j;
          vtb[((size_t)(gb * H_ + (c >> 5)) * DH_ + (c & 31)) * M_ + nn] =
              f2bf(acc[j] + bias4[j]);
        }
      }
      __syncthreads();
    }
  }
  grid_sync(cnt, 2 * NBLK);

  // ================= Phase A: flash attention (r9-verified body) ==============
  {
    u16* kvbase = (u16*)smem;               // [2][4096] u16
    u16* pbl = kvbase + 8192;               // plds [4][1024] u16
    float* prl = (float*)(kvbase + 12288);  // presence 1024 f32
    const int s = g >> 9;
    const int bh = (g >> 5) & 15;
    const int qblk = g & 31;
    const int b = bh >> 3, h = bh & 7;
    const int n0 = qblk * 64 + wv * 16;
    const int m0 = s * (M_ / SPLITS);
    const int NI = (M_ / SPLITS) / 64;  // 16

    const int gsk = (t & 3) ^ ((t >> 3) & 3);
    const u16* kst = kb + ((size_t)bh * M_ + m0 + (t >> 2)) * DH_ + gsk * 8;
    const int gsv = (t & 7) ^ ((t >> 3) & 7);
    const u16* vst = vtb + ((size_t)bh * DH_ + (t >> 3)) * M_ + m0 + gsv * 8;
    u16* const ldswK = kvbase + wv * 512;
    u16* const ldswV = kvbase + 2048 + wv * 512;

    const int ko0 = lr * 32 + (lg ^ ((lr >> 1) & 3)) * 8;
    const int sw = lr & 7;
    const int vo0 = (lg ^ sw) * 8;
    const int vo1 = ((4 + lg) ^ sw) * 8;

    const short8 qf = *(const short8*)(qb + ((size_t)bh * N_ + n0 + lr) * DH_ + lg * 8);
    u16* const plw = pbl + wv * 1024 + lr * 64;

    const f32x4 zz = {0.f, 0.f, 0.f, 0.f};
    f32x4 o0 = zz, o1 = zz, racc = zz;

    gload_lds16(kst, ldswK);
    gload_lds16(vst, ldswV);
    gload_lds16f(presence + (size_t)b * M_ + m0 + wv * 256 + lane * 4, prl + wv * 256);
    __syncthreads();

#pragma unroll 2
    for (int i = 0; i < NI; ++i) {
      const int mm = i * 64;
      const u16* kl = kvbase + (i & 1) * 4096;
      const u16* vl = kl + 2048;
      if (i + 1 < NI) {
        const int bo2 = ((i + 1) & 1) * 4096;
        gload_lds16(kst + (size_t)(i + 1) * (64 * DH_), ldswK + bo2);
        gload_lds16(vst + (size_t)(i + 1) * 64, ldswV + bo2);
      }

      f32x4 s4[4];
      __builtin_amdgcn_s_setprio(1);
#pragma unroll
      for (int tt = 0; tt < 4; ++tt) {
        const short8 kf = *(const short8*)(kl + tt * 512 + ko0);
        s4[tt] = __builtin_amdgcn_mfma_f32_16x16x32_bf16(kf, qf, zz, 0, 0, 0);
      }
      __builtin_amdgcn_s_setprio(0);

#pragma unroll
      for (int tt = 0; tt < 4; ++tt) {
        const f32x4 pr = *(const f32x4*)(prl + mm + tt * 16 + lg * 4);
#pragma unroll
        for (int j = 0; j < 4; ++j) s4[tt][j] = EXP2(s4[tt][j]);
        s4[tt] *= pr;  // exact 0 masked / identity present
        racc += s4[tt];
        const int slot = (2 * tt + (lg >> 1)) ^ sw;
        *(uint2*)(plw + slot * 8 + (lg & 1) * 4) =
            make_uint2(cvtpk_bf16(s4[tt][0], s4[tt][1]), cvtpk_bf16(s4[tt][2], s4[tt][3]));
      }
      const short8 pf0 = *(const short8*)(plw + vo0);
      const short8 pf1 = *(const short8*)(plw + vo1);
      const short8 vf0 = *(const short8*)(vl + lr * 64 + vo0);
      const short8 vf1 = *(const short8*)(vl + lr * 64 + vo1);
      const short8 vf2 = *(const short8*)(vl + (16 + lr) * 64 + vo0);
      const short8 vf3 = *(const short8*)(vl + (16 + lr) * 64 + vo1);
      __builtin_amdgcn_s_setprio(1);
      o0 = __builtin_amdgcn_mfma_f32_16x16x32_bf16(pf0, vf0, o0, 0, 0, 0);
      o0 = __builtin_amdgcn_mfma_f32_16x16x32_bf16(pf1, vf1, o0, 0, 0, 0);
      o1 = __builtin_amdgcn_mfma_f32_16x16x32_bf16(pf0, vf2, o1, 0, 0, 0);
      o1 = __builtin_amdgcn_mfma_f32_16x16x32_bf16(pf1, vf3, o1, 0, 0, 0);
      __builtin_amdgcn_s_setprio(0);
      __syncthreads();
    }

    float l = (racc[0] + racc[1]) + (racc[2] + racc[3]);
    l += __shfl_xor(l, 16);
    l += __shfl_xor(l, 32);
    if (lg == 0) lpart[((size_t)s * (B_ * N_) + b * N_ + n0 + lr) * H_ + h] = l;

    float* obp = opart + ((size_t)s * (B_ * N_) + (size_t)b * N_ + n0) * D_ + h * DH_;
#pragma unroll
    for (int j = 0; j < 4; ++j) {
      const int q = lg * 4 + j;
      obp[(size_t)q * D_ + lr] = o0[j];
      obp[(size_t)q * D_ + 16 + lr] = o1[j];
    }
  }
  grid_sync(cnt, 3 * NBLK);

  // ================= Phase O: output projection, 1024 32x32 tasks =============
  {
    u16* ws = (u16*)smem;
    u16* xsp = ws + 8192;
    const int nb = g & 127, cb = g >> 7;
    const int n0B = nb * 32, c0B = cb * 32;
    {  // DMA Wo^T slice (image 3)
      const u16* wsrc = wimg + (size_t)3 * 65536 + (size_t)c0B * D_ + t * 8;
#pragma unroll
      for (int i = 0; i < 4; ++i) gload_lds16(wsrc + i * 2048, ws + t * 8 + i * 2048);
    }
    {  // stage A = (opart0 + opart1) * (1/l), bf16 swizzled
      const int row = t >> 3, kc = (t & 7) * 32;
      const int gn = n0B + row;
      const int h0 = kc >> 5;
      const float il = 1.f / (lpart[(size_t)gn * H_ + h0] +
                              lpart[((size_t)(B_ * N_) + gn) * H_ + h0]);
      const float* o0p = opart + (size_t)gn * D_ + kc;
      const float* o1p = o0p + (size_t)(B_ * N_) * D_;
#pragma unroll
      for (int m = 0; m < 4; ++m) {
        f32x4 a = *(const f32x4*)(o0p + 8 * m) + *(const f32x4*)(o1p + 8 * m);
        f32x4 b2 = *(const f32x4*)(o0p + 8 * m + 4) + *(const f32x4*)(o1p + 8 * m + 4);
        a *= il;
        b2 *= il;
        uint4 v;
        v.x = cvtpk_bf16(a[0], a[1]);
        v.y = cvtpk_bf16(a[2], a[3]);
        v.z = cvtpk_bf16(b2[0], b2[1]);
        v.w = cvtpk_bf16(b2[2], b2[3]);
        const int sl = (kc >> 3) + m;
        *(uint4*)(xsp + row * 256 + ((sl ^ (row & 7)) * 8)) = v;
      }
    }
    __syncthreads();

    const f32x4 zz = {0.f, 0.f, 0.f, 0.f};
    f32x4 acc = zz;
    const int arow = (wv & 1) * 16 + lr;   // n
    const int brow = (wv >> 1) * 16 + lr;  // c
#pragma unroll
    for (int ks = 0; ks < 8; ++ks) {
      const short8 a = *(const short8*)(xsp + arow * 256 + (((ks * 4 + lg) ^ (arow & 7)) * 8));
      const short8 b = *(const short8*)(ws + brow * 256 + (((ks * 4 + lg) ^ (brow & 7)) * 8));
      acc = __builtin_amdgcn_mfma_f32_16x16x32_bf16(a, b, acc, 0, 0, 0);
    }
    // C: col(lr)=c, row(lg*4+j)=n -> coalesced f32 stores
    const int c = c0B + (wv >> 1) * 16 + lr;
    const int n = n0B + (wv & 1) * 16 + lg * 4;
    const float bb = bo[c];
#pragma unroll
    for (int j = 0; j < 4; ++j) out[(size_t)(n + j) * D_ + c] = acc[j] + bb;
  }
}

extern "C" void kernel_launch(void* const* d_in, const int* in_sizes, int n_in,
                              void* d_out, int out_size, void* d_ws, size_t ws_size,
                              hipStream_t stream) {
  (void)in_sizes; (void)n_in; (void)out_size; (void)ws_size;
  const float* queries  = (const float*)d_in[0];
  const float* keys     = (const float*)d_in[1];
  const float* values   = (const float*)d_in[2];
  const float* presence = (const float*)d_in[3];
  const float* Wq = (const float*)d_in[4];
  const float* bq = (const float*)d_in[5];
  const float* Wk = (const float*)d_in[6];
  const float* bk = (const float*)d_in[7];
  const float* Wv = (const float*)d_in[8];
  const float* bv = (const float*)d_in[9];
  const float* Wo = (const float*)d_in[10];
  const float* bo = (const float*)d_in[11];

  // ws: cnt(256B) | ximg 6MB | wimg 0.5MB | qb/kb/vtb 6MB | opart 8MB | lpart 256KB
  u32* cnt  = (u32*)d_ws;
  u16* ximg = (u16*)d_ws + 128;
  u16* wimg = ximg + (size_t)3 * 4096 * D_;
  u16* qb   = wimg + (size_t)4 * D_ * D_;
  u16* kb   = qb + (size_t)B_ * H_ * N_ * DH_;
  u16* vtb  = kb + (size_t)B_ * H_ * M_ * DH_;
  float* opart = (float*)(vtb + (size_t)B_ * H_ * DH_ * M_);
  float* lpart = opart + (size_t)SPLITS * B_ * N_ * D_;

  hipMemsetAsync(d_ws, 0, 256, stream);
  fused_kernel<<<NBLK, 256, 0, stream>>>(
      queries, keys, values, Wq, Wk, Wv, Wo, bq, bk, bv, bo, presence,
      ximg, wimg, qb, kb, vtb, opart, lpart, (float*)d_out, cnt);
}

// Round 12
// 52.772 us; speedup vs baseline: 15.8737x; 15.8737x over previous
//
#include <hip/hip_runtime.h>

#define B_ 2
#define N_ 2048
#define M_ 2048
#define D_ 256
#define H_ 8
#define DH_ 32
#define SPLITS 4
// 1/sqrt(32) * log2(e): fold into q projection; attention works in exp2 domain
#define QSCALE (0.17677669529663689f * 1.4426950408889634f)

typedef __attribute__((ext_vector_type(8))) short short8;
typedef __attribute__((ext_vector_type(4))) float f32x4;
typedef unsigned short u16;
typedef unsigned int u32;

#if __has_builtin(__builtin_amdgcn_exp2f)
#define EXP2 __builtin_amdgcn_exp2f
#else
#define EXP2 exp2f
#endif

__device__ __forceinline__ u16 f2bf(float f) {
  u32 u = __float_as_uint(f);
  return (u16)((u + 0x7fffu + ((u >> 16) & 1u)) >> 16);  // RNE
}
__device__ __forceinline__ u32 cvtpk_bf16(float lo, float hi) {
  u32 r;
  asm("v_cvt_pk_bf16_f32 %0, %1, %2" : "=v"(r) : "v"(lo), "v"(hi));
  return r;
}
__device__ __forceinline__ void gload_lds16(const u16* g, u16* l) {
  __builtin_amdgcn_global_load_lds((const __attribute__((address_space(1))) void*)g,
                                   (__attribute__((address_space(3))) void*)l, 16, 0, 0);
}

// ---------- K1: fused q/k/v projection (r7 version, best measured) ----------
// block = 64 c x 64 n, 4 waves. W transpose-converted to LDS bf16 (swizzled);
// X converted to LDS bf16 (swizzled). Outputs: q/k [bh][n][32] (q * QSCALE),
// v transposed [bh][32][M].
__global__ __launch_bounds__(256, 2) void qkvproj_kernel(
    const float* __restrict__ Xq, const float* __restrict__ Xk, const float* __restrict__ Xv,
    const float* __restrict__ Wq, const float* __restrict__ Wk, const float* __restrict__ Wv,
    const float* __restrict__ bq, const float* __restrict__ bk, const float* __restrict__ bv,
    u16* __restrict__ qb, u16* __restrict__ kb, u16* __restrict__ vtb) {
  __shared__ u16 wsT[64 * 256];  // [c][k] = W[k][c], 16B-slot swizzle (k>>3)^(c&7)
  __shared__ u16 xs[64 * 256];   // [n][k] = X[n][k], swizzle (k>>3)^(n&7)
  const int p = blockIdx.y;
  const int nb = blockIdx.x & 63, cb = blockIdx.x >> 6;
  const int n0B = nb * 64, c0B = cb * 64;
  const float* X = p == 0 ? Xq : (p == 1 ? Xk : Xv);
  const float* W = p == 0 ? Wq : (p == 1 ? Wk : Wv);
  const float* bias = p == 0 ? bq : (p == 1 ? bk : bv);
  const int t = threadIdx.x;

  {  // stage W^T
    const int cL = (t & 15) * 4, kB = (t >> 4) * 16;
    const float* wp = W + (size_t)kB * D_ + c0B + cL;
#pragma unroll
    for (int u = 0; u < 4; ++u) {
      const int k0 = kB + 4 * u;
      const f32x4 w0 = *(const f32x4*)(wp + (size_t)(4 * u + 0) * D_);
      const f32x4 w1 = *(const f32x4*)(wp + (size_t)(4 * u + 1) * D_);
      const f32x4 w2 = *(const f32x4*)(wp + (size_t)(4 * u + 2) * D_);
      const f32x4 w3 = *(const f32x4*)(wp + (size_t)(4 * u + 3) * D_);
#pragma unroll
      for (int cc = 0; cc < 4; ++cc) {
        const int c = cL + cc;
        uint2 v;
        v.x = cvtpk_bf16(w0[cc], w1[cc]);
        v.y = cvtpk_bf16(w2[cc], w3[cc]);
        *(uint2*)(wsT + c * 256 + (((k0 >> 3) ^ (c & 7)) * 8) + (k0 & 7)) = v;
      }
    }
  }
  {  // stage X
    const int nL = t >> 2, k64 = (t & 3) * 64;
    const float* xp = X + (size_t)(n0B + nL) * D_ + k64;
#pragma unroll
    for (int m = 0; m < 8; ++m) {
      const f32x4 a = *(const f32x4*)(xp + 8 * m);
      const f32x4 b2 = *(const f32x4*)(xp + 8 * m + 4);
      uint4 v;
      v.x = cvtpk_bf16(a[0], a[1]);
      v.y = cvtpk_bf16(a[2], a[3]);
      v.z = cvtpk_bf16(b2[0], b2[1]);
      v.w = cvtpk_bf16(b2[2], b2[3]);
      const int k0 = k64 + 8 * m;
      *(uint4*)(xs + nL * 256 + (((k0 >> 3) ^ (nL & 7)) * 8)) = v;
    }
  }
  __syncthreads();

  const int wv = t >> 6, lane = t & 63, lr = lane & 15, lg = lane >> 4;
  const f32x4 zz = {0.f, 0.f, 0.f, 0.f};
  f32x4 acc[4] = {zz, zz, zz, zz};
  const int arow = wv * 16 + lr;
#pragma unroll
  for (int ks = 0; ks < 8; ++ks) {
    const short8 a = *(const short8*)(wsT + arow * 256 + (((ks * 4 + lg) ^ (arow & 7)) * 8));
#pragma unroll
    for (int ng = 0; ng < 4; ++ng) {
      const int brow = ng * 16 + lr;
      const short8 b = *(const short8*)(xs + brow * 256 + (((ks * 4 + lg) ^ (brow & 7)) * 8));
      acc[ng] = __builtin_amdgcn_mfma_f32_16x16x32_bf16(a, b, acc[ng], 0, 0, 0);
    }
  }

  // D layout: col(lr)=n, row(lg*4+j)=c
  const int cg4 = c0B + wv * 16 + lg * 4;
  const f32x4 bias4 = *(const f32x4*)(bias + cg4);
  if (p < 2) {
    u16* ob = p == 0 ? qb : kb;
    const float sc = p == 0 ? QSCALE : 1.0f;
#pragma unroll
    for (int ng = 0; ng < 4; ++ng) {
      const int n = n0B + ng * 16 + lr;
      const int b = n >> 11, nn = n & (N_ - 1);
#pragma unroll
      for (int j = 0; j < 4; ++j) {
        const int c = cg4 + j;
        ob[((size_t)(b * H_ + (c >> 5)) * N_ + nn) * DH_ + (c & 31)] =
            f2bf((acc[ng][j] + bias4[j]) * sc);
      }
    }
  } else {
#pragma unroll
    for (int ng = 0; ng < 4; ++ng) {
      const int n = n0B + ng * 16 + lr;
      const int b = n >> 11, nn = n & (M_ - 1);
#pragma unroll
      for (int j = 0; j < 4; ++j) {
        const int c = cg4 + j;
        vtb[((size_t)(b * H_ + (c >> 5)) * DH_ + (c & 31)) * M_ + nn] =
            f2bf(acc[ng][j] + bias4[j]);
      }
    }
  }
}

// ---------- K2: flash attention (r7 body verbatim; key-split 4 for occupancy) ----
// grid = 4 splits x 16 bh x 32 qtiles = 2048 blocks (~6/CU resident);
// block = 256 thr = 4 waves, 16 q-rows each; 8 chunks of 64 keys per block.
__global__ __launch_bounds__(256, 4) void attn_kernel(
    const u16* __restrict__ qb, const u16* __restrict__ kb,
    const u16* __restrict__ vtb, const float* __restrict__ presence,
    float* __restrict__ opart, float* __restrict__ lpart) {
  __shared__ u16 kvlds[2][4096];  // [buf]: K[64 keys][32 d] swz | V[32 d][64 keys] swz
  __shared__ u16 plds[4][1024];   // per-wave P tile [16 q][64 k], swizzled
  const int t = threadIdx.x;
  const int wv = t >> 6, lane = t & 63;
  const int lr = lane & 15, lg = lane >> 4;
  const int s = blockIdx.x >> 9;
  const int bh = (blockIdx.x >> 5) & 15;
  const int qblk = blockIdx.x & 31;
  const int b = bh >> 3, h = bh & 7;
  const int n0 = qblk * 64 + wv * 16;
  const int m0 = s * (M_ / SPLITS);
  const int NI = (M_ / SPLITS) / 64;  // 8 chunks

  // staging sources (per-lane, pre-swizzled)
  const int gsk = (t & 3) ^ ((t >> 3) & 3);
  const u16* kst = kb + ((size_t)bh * M_ + m0 + (t >> 2)) * DH_ + gsk * 8;
  const int gsv = (t & 7) ^ ((t >> 3) & 7);
  const u16* vst = vtb + ((size_t)bh * DH_ + (t >> 3)) * M_ + m0 + gsv * 8;
  u16* const ldswK = &kvlds[0][0] + wv * 512;         // + buf*4096
  u16* const ldswV = &kvlds[0][0] + 2048 + wv * 512;  // + buf*4096

  // per-lane LDS fragment read offsets (u16 units)
  const int ko0 = lr * 32 + (lg ^ ((lr >> 1) & 3)) * 8;  // K: + tt*512
  const int sw = lr & 7;
  const int vo0 = (lg ^ sw) * 8;        // keys lg*8
  const int vo1 = ((4 + lg) ^ sw) * 8;  // keys 32+lg*8

  // Q as B-frag of S^T: col=query=lr, k=d=lg*8+j
  const short8 qf = *(const short8*)(qb + ((size_t)bh * N_ + n0 + lr) * DH_ + lg * 8);
  const float* pbase = presence + (size_t)b * M_ + m0 + lg * 4;
  u16* const plw = plds[wv] + lr * 64;

  const f32x4 zz = {0.f, 0.f, 0.f, 0.f};
  f32x4 o0 = zz, o1 = zz, racc = zz;

  gload_lds16(kst, ldswK);  // chunk 0 -> buf 0
  gload_lds16(vst, ldswV);
  __syncthreads();

#pragma unroll 2
  for (int i = 0; i < NI; ++i) {
    const int mm = i * 64;
    const u16* kl = &kvlds[i & 1][0];
    const u16* vl = &kvlds[i & 1][2048];
    // presence first (its vmcnt wait must not drain the stage-DMA below)
    f32x4 pr[4];
#pragma unroll
    for (int tt = 0; tt < 4; ++tt) pr[tt] = *(const f32x4*)(pbase + mm + tt * 16);
    if (i + 1 < NI) {  // prefetch chunk i+1 into other buffer
      const int bo = ((i + 1) & 1) * 4096;
      gload_lds16(kst + (size_t)(i + 1) * (64 * DH_), ldswK + bo);
      gload_lds16(vst + (size_t)(i + 1) * 64, ldswV + bo);
    }

    f32x4 s4[4];
    __builtin_amdgcn_s_setprio(1);
#pragma unroll
    for (int tt = 0; tt < 4; ++tt) {
      const short8 kf = *(const short8*)(kl + tt * 512 + ko0);
      s4[tt] = __builtin_amdgcn_mfma_f32_16x16x32_bf16(kf, qf, zz, 0, 0, 0);
    }
    __builtin_amdgcn_s_setprio(0);

#pragma unroll
    for (int tt = 0; tt < 4; ++tt) {
      s4[tt] += (pr[tt] - 1.f) * 1e30f;  // exact 0 present / -1e30 masked
#pragma unroll
      for (int j = 0; j < 4; ++j) s4[tt][j] = EXP2(s4[tt][j]);
      racc += s4[tt];
      const int slot = (2 * tt + (lg >> 1)) ^ sw;
      *(uint2*)(plw + slot * 8 + (lg & 1) * 4) =
          make_uint2(cvtpk_bf16(s4[tt][0], s4[tt][1]), cvtpk_bf16(s4[tt][2], s4[tt][3]));
    }
    // immediate PV (wave-private P tile; compiler orders via lgkmcnt)
    const short8 pf0 = *(const short8*)(plw + vo0);
    const short8 pf1 = *(const short8*)(plw + vo1);
    const short8 vf0 = *(const short8*)(vl + lr * 64 + vo0);
    const short8 vf1 = *(const short8*)(vl + lr * 64 + vo1);
    const short8 vf2 = *(const short8*)(vl + (16 + lr) * 64 + vo0);
    const short8 vf3 = *(const short8*)(vl + (16 + lr) * 64 + vo1);
    __builtin_amdgcn_s_setprio(1);
    o0 = __builtin_amdgcn_mfma_f32_16x16x32_bf16(pf0, vf0, o0, 0, 0, 0);
    o0 = __builtin_amdgcn_mfma_f32_16x16x32_bf16(pf1, vf1, o0, 0, 0, 0);
    o1 = __builtin_amdgcn_mfma_f32_16x16x32_bf16(pf0, vf2, o1, 0, 0, 0);
    o1 = __builtin_amdgcn_mfma_f32_16x16x32_bf16(pf1, vf3, o1, 0, 0, 0);
    __builtin_amdgcn_s_setprio(0);
    __syncthreads();
  }

  float l = (racc[0] + racc[1]) + (racc[2] + racc[3]);
  l += __shfl_xor(l, 16);
  l += __shfl_xor(l, 32);
  if (lg == 0) lpart[((size_t)s * (B_ * N_) + b * N_ + n0 + lr) * H_ + h] = l;

  float* ob = opart + ((size_t)s * (B_ * N_) + (size_t)b * N_ + n0) * D_ + h * DH_;
#pragma unroll
  for (int j = 0; j < 4; ++j) {
    const int q = lg * 4 + j;
    ob[(size_t)q * D_ + lr] = o0[j];
    ob[(size_t)q * D_ + 16 + lr] = o1[j];
  }
}

// ---------- K3: output projection (combine 4 splits, normalize, MFMA; r10 version) ----
__global__ __launch_bounds__(256, 2) void projo_kernel(
    const float* __restrict__ opart, const float* __restrict__ lpart,
    const float* __restrict__ Wo, const float* __restrict__ bo,
    float* __restrict__ out) {
  __shared__ u16 wsT[64 * 256];  // Wo^T [c][k] swizzled
  __shared__ u16 xs[64 * 256];   // normalized attention output [n][k] swizzled
  const int nb = blockIdx.x & 63, cb = blockIdx.x >> 6;
  const int n0B = nb * 64, c0B = cb * 64;
  const int t = threadIdx.x;

  {  // stage Wo^T
    const int cL = (t & 15) * 4, kB = (t >> 4) * 16;
    const float* wp = Wo + (size_t)kB * D_ + c0B + cL;
#pragma unroll
    for (int u = 0; u < 4; ++u) {
      const int k0 = kB + 4 * u;
      const f32x4 w0 = *(const f32x4*)(wp + (size_t)(4 * u + 0) * D_);
      const f32x4 w1 = *(const f32x4*)(wp + (size_t)(4 * u + 1) * D_);
      const f32x4 w2 = *(const f32x4*)(wp + (size_t)(4 * u + 2) * D_);
      const f32x4 w3 = *(const f32x4*)(wp + (size_t)(4 * u + 3) * D_);
#pragma unroll
      for (int cc = 0; cc < 4; ++cc) {
        const int c = cL + cc;
        uint2 v;
        v.x = cvtpk_bf16(w0[cc], w1[cc]);
        v.y = cvtpk_bf16(w2[cc], w3[cc]);
        *(uint2*)(wsT + c * 256 + (((k0 >> 3) ^ (c & 7)) * 8) + (k0 & 7)) = v;
      }
    }
  }
  {  // stage A = (sum of 4 split partials) * (1/l), bf16 swizzled
    const int nL = t >> 2, k64 = (t & 3) * 64;
    const int gn = n0B + nL;
    const int h0 = k64 >> 5;
    float l0s = 0.f, l1s = 0.f;
#pragma unroll
    for (int sp = 0; sp < SPLITS; ++sp) {
      l0s += lpart[((size_t)sp * (B_ * N_) + gn) * H_ + h0];
      l1s += lpart[((size_t)sp * (B_ * N_) + gn) * H_ + h0 + 1];
    }
    const float il0 = 1.f / l0s, il1 = 1.f / l1s;
    const float* obase = opart + (size_t)gn * D_ + k64;
#pragma unroll
    for (int m = 0; m < 8; ++m) {
      f32x4 a = {0.f, 0.f, 0.f, 0.f};
      f32x4 b2 = {0.f, 0.f, 0.f, 0.f};
#pragma unroll
      for (int sp = 0; sp < SPLITS; ++sp) {
        const float* op = obase + (size_t)sp * (B_ * N_) * D_;
        a += *(const f32x4*)(op + 8 * m);
        b2 += *(const f32x4*)(op + 8 * m + 4);
      }
      const float il = (m < 4) ? il0 : il1;
      a *= il;
      b2 *= il;
      uint4 v;
      v.x = cvtpk_bf16(a[0], a[1]);
      v.y = cvtpk_bf16(a[2], a[3]);
      v.z = cvtpk_bf16(b2[0], b2[1]);
      v.w = cvtpk_bf16(b2[2], b2[3]);
      const int k0 = k64 + 8 * m;
      *(uint4*)(xs + nL * 256 + (((k0 >> 3) ^ (nL & 7)) * 8)) = v;
    }
  }
  __syncthreads();

  const int wv = t >> 6, lane = t & 63, lr = lane & 15, lg = lane >> 4;
  const f32x4 zz = {0.f, 0.f, 0.f, 0.f};
  f32x4 acc[4] = {zz, zz, zz, zz};
  const int arow = wv * 16 + lr;
#pragma unroll
  for (int ks = 0; ks < 8; ++ks) {
    const short8 a = *(const short8*)(xs + arow * 256 + (((ks * 4 + lg) ^ (arow & 7)) * 8));
#pragma unroll
    for (int ng = 0; ng < 4; ++ng) {
      const int brow = ng * 16 + lr;
      const short8 bfr = *(const short8*)(wsT + brow * 256 + (((ks * 4 + lg) ^ (brow & 7)) * 8));
      acc[ng] = __builtin_amdgcn_mfma_f32_16x16x32_bf16(a, bfr, acc[ng], 0, 0, 0);
    }
  }
  // D layout: col(lr)=c, row(lg*4+j)=n -> coalesced f32 stores
#pragma unroll
  for (int ng = 0; ng < 4; ++ng) {
    const int c = c0B + ng * 16 + lr;
    const float bb = bo[c];
#pragma unroll
    for (int j = 0; j < 4; ++j)
      out[(size_t)(n0B + wv * 16 + lg * 4 + j) * D_ + c] = acc[ng][j] + bb;
  }
}

extern "C" void kernel_launch(void* const* d_in, const int* in_sizes, int n_in,
                              void* d_out, int out_size, void* d_ws, size_t ws_size,
                              hipStream_t stream) {
  (void)in_sizes; (void)n_in; (void)out_size; (void)ws_size;
  const float* queries  = (const float*)d_in[0];
  const float* keys     = (const float*)d_in[1];
  const float* values   = (const float*)d_in[2];
  const float* presence = (const float*)d_in[3];
  const float* Wq = (const float*)d_in[4];
  const float* bq = (const float*)d_in[5];
  const float* Wk = (const float*)d_in[6];
  const float* bk = (const float*)d_in[7];
  const float* Wv = (const float*)d_in[8];
  const float* bv = (const float*)d_in[9];
  const float* Wo = (const float*)d_in[10];
  const float* bo = (const float*)d_in[11];

  // ws: qb 2MB | kb 2MB | vtb 2MB | opart 16MB | lpart 512KB
  u16* qb  = (u16*)d_ws;
  u16* kb  = qb + (size_t)B_ * H_ * N_ * DH_;
  u16* vtb = kb + (size_t)B_ * H_ * M_ * DH_;
  float* opart = (float*)(vtb + (size_t)B_ * H_ * DH_ * M_);
  float* lpart = opart + (size_t)SPLITS * B_ * N_ * D_;

  qkvproj_kernel<<<dim3(256, 3), 256, 0, stream>>>(
      queries, keys, values, Wq, Wk, Wv, bq, bk, bv, qb, kb, vtb);
  attn_kernel<<<SPLITS * 16 * 32, 256, 0, stream>>>(qb, kb, vtb, presence, opart, lpart);
  projo_kernel<<<256, 256, 0, stream>>>(opart, lpart, Wo, bo, (float*)d_out);
}